// Round 4
// baseline (293.651 us; speedup 1.0000x reference)
//
#include <hip/hip_runtime.h>
#include <math.h>

#define BSZ 32
#define NSL 1024
#define HS  768
#define BM  128
#define BK  32
#define NKS (HS / BK)            // 24
#define NTILE (NSL / BM)         // 8
#define TILES_PER_BATCH 36       // upper-tri incl diag of 8x8
#define NWG (BSZ * TILES_PER_BATCH)  // 1152

typedef __attribute__((ext_vector_type(8))) unsigned short u16x8;
typedef __attribute__((ext_vector_type(4))) float f32x4;

__device__ __forceinline__ unsigned short f2bf(float x) {
  unsigned u = __float_as_uint(x);
  unsigned r = (u + 0x7FFFu + ((u >> 16) & 1u)) >> 16;   // round-to-nearest-even
  return (unsigned short)r;
}

__device__ __forceinline__ void gload_lds16(const void* g, void* l) {
  __builtin_amdgcn_global_load_lds((__attribute__((address_space(1))) void*)(void*)g,
                                   (__attribute__((address_space(3))) void*)l, 16, 0, 0);
}

// ---------------- mask dtype detection (bool8 vs int32 vs f32 0/1) -------------
__global__ void detect_kernel(const unsigned int* __restrict__ mraw, int* __restrict__ flag) {
  __shared__ int okInt, okF32;
  if (threadIdx.x == 0) { okInt = 1; okF32 = 1; }
  __syncthreads();
  int badI = 0, badF = 0;
  // scan first 32KB only (safe under every layout interpretation)
  for (int i = threadIdx.x; i < 8192; i += 256) {
    unsigned v = mraw[i];
    if (v != 0u && v != 1u) badI = 1;
    if (v != 0u && v != 0x3F800000u) badF = 1;
  }
  if (badI) atomicAnd(&okInt, 0);
  if (badF) atomicAnd(&okF32, 0);
  __syncthreads();
  if (threadIdx.x == 0) *flag = okInt ? 0 : (okF32 ? 1 : 2);
}

__device__ __forceinline__ float mask_at(const void* mraw, int f, int idx) {
  bool m;
  if (f == 0)      m = ((const int*)mraw)[idx] != 0;
  else if (f == 1) m = ((const float*)mraw)[idx] != 0.0f;
  else             m = ((const unsigned char*)mraw)[idx] != 0;
  return m ? 1.0f : 0.0f;
}

// --------- normalize rows; write bf16 Xn (or just inv-norms if ws small) -------
__global__ __launch_bounds__(256) void norm_kernel(const float* __restrict__ embeds,
                                                   unsigned short* __restrict__ xn,
                                                   float* __restrict__ invn,
                                                   int writeXn) {
  int w = threadIdx.x >> 6, lane = threadIdx.x & 63;
  int row = blockIdx.x * 4 + w;                      // < 32768
  const float* src = embeds + (size_t)row * HS;
  float4 v[3];
  float ss = 0.0f;
  #pragma unroll
  for (int q = 0; q < 3; ++q) {
    v[q] = *(const float4*)(src + q * 256 + lane * 4);
    ss += v[q].x * v[q].x + v[q].y * v[q].y + v[q].z * v[q].z + v[q].w * v[q].w;
  }
  #pragma unroll
  for (int off = 32; off; off >>= 1) ss += __shfl_xor(ss, off);
  float inv = 1.0f / fmaxf(sqrtf(ss), 1e-8f);
  if (writeXn) {
    unsigned short* dst = xn + (size_t)row * HS;
    #pragma unroll
    for (int q = 0; q < 3; ++q) {
      ushort4 h;
      h.x = f2bf(v[q].x * inv); h.y = f2bf(v[q].y * inv);
      h.z = f2bf(v[q].z * inv); h.w = f2bf(v[q].w * inv);
      *(ushort4*)(dst + q * 256 + lane * 4) = h;
    }
  } else if (lane == 0) {
    invn[row] = inv;
  }
}

// ---------------- fused Gram + masked relative-loss reduction ------------------
// One WG per (batch, upper-tri 128x128 tile pair). 4 waves in 2x2, each owns a
// 64x64 sub-tile as 4x4 frags of 16x16x32 bf16 MFMA. LDS tiles double-buffered
// [2][128][BK] with 16B-chunk XOR swizzle: chunk c of row r at pos c^((r>>1)&3)
// (applied on pre-swizzled GLOBAL source so global_load_lds dest stays linear;
// same XOR on the ds_read side — rule #21 both-sides involution).
// T3-minimum 2-phase: issue next tile's staging BEFORE current tile's compute.
// Diagonal WGs also popcount their rows into cnt[b]; the LAST WG (device-scope
// done counter) computes the final loss — no separate finish kernel.
template<int STAGE_F32>
__global__ __launch_bounds__(256) void gram_kernel(const float* __restrict__ embeds,
                                                   const unsigned short* __restrict__ xn,
                                                   const float* __restrict__ invn,
                                                   const int* __restrict__ gt,
                                                   const void* __restrict__ mraw,
                                                   const int* __restrict__ flag,
                                                   float* __restrict__ num,
                                                   float* __restrict__ cnt,
                                                   int* __restrict__ done,
                                                   float* __restrict__ out) {
  __shared__ __align__(16) unsigned short lA[2][BM * BK];   // 2 x 8 KB
  __shared__ __align__(16) unsigned short lB[2][BM * BK];   // 2 x 8 KB
  __shared__ float gtR[BM], gtC[BM], mR[BM], mC[BM], ivR[BM], ivC[BM];
  __shared__ float red[4];
  __shared__ int lastFlag;

  // XCD-aware swizzle (NWG % 8 == 0 -> bijective): contiguous tiles per XCD
  int blk = blockIdx.x;
  int swz = (blk & 7) * (NWG / 8) + (blk >> 3);
  int b = swz / TILES_PER_BATCH;
  int t = swz % TILES_PER_BATCH;
  int ti = 0;
  { int c = NTILE; while (t >= c) { t -= c; --c; ++ti; } }
  int tj = ti + t;

  const int tid = threadIdx.x;
  const int w = tid >> 6;
  const int lane = tid & 63;
  const int wr = w >> 1, wc = w & 1;
  const int Ra = ti * BM, Rb = tj * BM;

  if (tid < BM) {
    int f = *flag;
    int ia = b * NSL + Ra + tid;
    int ib = b * NSL + Rb + tid;
    gtR[tid] = (float)gt[ia]; mR[tid] = mask_at(mraw, f, ia);
    gtC[tid] = (float)gt[ib]; mC[tid] = mask_at(mraw, f, ib);
    if constexpr (STAGE_F32 != 0) { ivR[tid] = invn[ia]; ivC[tid] = invn[ib]; }
  }

  f32x4 acc[4][4];
  #pragma unroll
  for (int m = 0; m < 4; ++m)
    #pragma unroll
    for (int n = 0; n < 4; ++n)
      #pragma unroll
      for (int r = 0; r < 4; ++r) acc[m][n][r] = 0.0f;

  auto stage = [&](int buf, int ks) {
    const int kbase = ks * BK;
    #pragma unroll
    for (int q = 0; q < 2; ++q) {
      int L = q * 256 + tid;            // linear 16B-chunk index 0..511
      int row = L >> 2, pos = L & 3;
      int c = pos ^ ((row >> 1) & 3);   // pre-swizzled global source
      if constexpr (STAGE_F32 == 0) {
        const unsigned short* gaA = xn + (size_t)(b * NSL + Ra + row) * HS + kbase + c * 8;
        const unsigned short* gaB = xn + (size_t)(b * NSL + Rb + row) * HS + kbase + c * 8;
        unsigned short* ldA = &lA[buf][(q * 256 + w * 64) * 8];  // wave-uniform base
        unsigned short* ldB = &lB[buf][(q * 256 + w * 64) * 8];
        gload_lds16(gaA, ldA);
        gload_lds16(gaB, ldB);
      } else {
        const float* gaA = embeds + (size_t)(b * NSL + Ra + row) * HS + kbase + c * 8;
        const float* gaB = embeds + (size_t)(b * NSL + Rb + row) * HS + kbase + c * 8;
        float4 a0 = *(const float4*)gaA;
        float4 a1 = *(const float4*)(gaA + 4);
        float4 b0 = *(const float4*)gaB;
        float4 b1 = *(const float4*)(gaB + 4);
        float sa = ivR[row], sb = ivC[row];
        u16x8 ha, hb;
        ha[0] = f2bf(a0.x * sa); ha[1] = f2bf(a0.y * sa);
        ha[2] = f2bf(a0.z * sa); ha[3] = f2bf(a0.w * sa);
        ha[4] = f2bf(a1.x * sa); ha[5] = f2bf(a1.y * sa);
        ha[6] = f2bf(a1.z * sa); ha[7] = f2bf(a1.w * sa);
        hb[0] = f2bf(b0.x * sb); hb[1] = f2bf(b0.y * sb);
        hb[2] = f2bf(b0.z * sb); hb[3] = f2bf(b0.w * sb);
        hb[4] = f2bf(b1.x * sb); hb[5] = f2bf(b1.y * sb);
        hb[6] = f2bf(b1.z * sb); hb[7] = f2bf(b1.w * sb);
        *(u16x8*)&lA[buf][row * BK + pos * 8] = ha;
        *(u16x8*)&lB[buf][row * BK + pos * 8] = hb;
      }
    }
  };

  if constexpr (STAGE_F32 != 0) __syncthreads();   // ivR/ivC ready before stage
  stage(0, 0);
  __syncthreads();   // prologue drain (also covers gtR/mR stores)

  int cur = 0;
  for (int ks = 0; ks < NKS; ++ks) {
    if (ks + 1 < NKS) stage(cur ^ 1, ks + 1);   // issue-early: in flight across compute

    u16x8 af[4], bfv[4];
    const int kc = lane >> 4;
    #pragma unroll
    for (int m = 0; m < 4; ++m) {
      int row = wr * 64 + m * 16 + (lane & 15);
      af[m] = *(const u16x8*)&lA[cur][row * BK + ((kc ^ ((row >> 1) & 3)) * 8)];
    }
    #pragma unroll
    for (int n = 0; n < 4; ++n) {
      int row = wc * 64 + n * 16 + (lane & 15);
      bfv[n] = *(const u16x8*)&lB[cur][row * BK + ((kc ^ ((row >> 1) & 3)) * 8)];
    }
    #pragma unroll
    for (int m = 0; m < 4; ++m)
      #pragma unroll
      for (int n = 0; n < 4; ++n)
        asm volatile("v_mfma_f32_16x16x32_bf16 %0, %1, %2, %0"
                     : "+v"(acc[m][n]) : "v"(af[m]), "v"(bfv[n]));
    __syncthreads();   // next buffer staged + this buffer's reads complete
    cur ^= 1;
  }

  asm volatile("s_nop 7\n\ts_nop 7");   // MFMA->VALU read hazard insurance

  // fused epilogue: D layout col=lane&15, row=(lane>>4)*4+reg (verified m89/m91)
  float lsum = 0.0f;
  const bool diag = (ti == tj);
  #pragma unroll
  for (int m = 0; m < 4; ++m) {
    #pragma unroll
    for (int n = 0; n < 4; ++n) {
      int ljl = wc * 64 + n * 16 + (lane & 15);
      float gj = gtC[ljl], mj = mC[ljl];
      #pragma unroll
      for (int r = 0; r < 4; ++r) {
        int lil = wr * 64 + m * 16 + (lane >> 4) * 4 + r;
        float gi = gtR[lil], mi_ = mR[lil];
        float cosd = 1.0f - acc[m][n][r];
        float vd = 2.0f * fabsf(gi - gj) / (fabsf(gi) + fabsf(gj) + 1e-18f);
        float d = cosd - vd;
        float pm = mi_ * mj;
        if (diag) pm = (lil < ljl) ? pm : 0.0f;   // strict upper triangle
        lsum += d * d * pm;
      }
    }
  }
  #pragma unroll
  for (int off = 32; off; off >>= 1) lsum += __shfl_down(lsum, off);
  if (lane == 0) red[w] = lsum;
  __syncthreads();
  if (tid == 0) atomicAdd(&num[b], red[0] + red[1] + red[2] + red[3]);

  // diagonal WGs contribute this 128-row slice's mask popcount
  if (diag) {   // WG-uniform condition -> barriers inside are legal
    __syncthreads();   // tid0's read of red[] for num must complete before reuse
    float pc = (tid < BM) ? mR[tid] : 0.0f;
    #pragma unroll
    for (int off = 32; off; off >>= 1) pc += __shfl_down(pc, off);
    if (lane == 0) red[w] = pc;
    __syncthreads();
    if (tid == 0) atomicAdd(&cnt[b], red[0] + red[1] + red[2] + red[3]);
  }

  // completion: last WG computes the loss (device-scope atomics, m20/G12)
  __threadfence();
  if (tid == 0) {
    int old = atomicAdd(done, 1);
    lastFlag = (old == NWG - 1);
  }
  __syncthreads();
  if (lastFlag && w == 0) {
    float v = 0.0f;
    if (lane < BSZ) {
      float n = atomicAdd(&num[lane], 0.0f);   // coherent read-latest
      float c = atomicAdd(&cnt[lane], 0.0f);
      float den = 0.5f * c * (c - 1.0f) + 1e-13f;   // sum(pair_mask) == C(m,2)
      v = sqrtf(n / den);
    }
    #pragma unroll
    for (int off = 32; off; off >>= 1) v += __shfl_down(v, off);
    if (lane == 0) out[0] = v * (1.0f / 32.0f);
  }
}

extern "C" void kernel_launch(void* const* d_in, const int* in_sizes, int n_in,
                              void* d_out, int out_size, void* d_ws, size_t ws_size,
                              hipStream_t stream) {
  const float* embeds = (const float*)d_in[0];
  const int* gt = (const int*)d_in[1];
  const void* mask = d_in[2];
  float* out = (float*)d_out;

  char* ws = (char*)d_ws;
  float* num   = (float*)(ws + 0);                 // 32 f32
  float* cnt   = (float*)(ws + 128);               // 32 f32
  int*   flag  = (int*)(ws + 256);
  int*   done  = (int*)(ws + 260);
  float* invn  = (float*)(ws + 512);               // 128 KB (fallback path only)
  unsigned short* xn = (unsigned short*)(ws + 512 + 131072);  // 48 MB, 16B aligned
  const size_t need_xn = 512 + 131072 + (size_t)BSZ * NSL * HS * 2;

  hipMemsetAsync(d_ws, 0, 512, stream);
  detect_kernel<<<1, 256, 0, stream>>>((const unsigned int*)mask, flag);

  int useXn = (ws_size >= need_xn) ? 1 : 0;
  norm_kernel<<<BSZ * NSL / 4, 256, 0, stream>>>(embeds, xn, invn, useXn);
  if (useXn)
    gram_kernel<0><<<NWG, 256, 0, stream>>>(embeds, xn, invn, gt, mask, flag, num, cnt, done, out);
  else
    gram_kernel<1><<<NWG, 256, 0, stream>>>(embeds, xn, invn, gt, mask, flag, num, cnt, done, out);
}

// Round 7
// 285.493 us; speedup vs baseline: 1.0286x; 1.0286x over previous
//
#include <hip/hip_runtime.h>
#include <math.h>

#define BSZ 32
#define NSL 1024
#define HS  768
#define BM  128
#define BK  32
#define NKS (HS / BK)            // 24
#define NTILE (NSL / BM)         // 8
#define TILES_PER_BATCH 36       // upper-tri incl diag of 8x8
#define NWG (BSZ * TILES_PER_BATCH)  // 1152
#define NORM_BLOCKS (BSZ * NSL / 4)  // 8192

typedef __attribute__((ext_vector_type(8))) unsigned short u16x8;
typedef __attribute__((ext_vector_type(4))) float f32x4;

__device__ __forceinline__ unsigned short f2bf(float x) {
  unsigned u = __float_as_uint(x);
  unsigned r = (u + 0x7FFFu + ((u >> 16) & 1u)) >> 16;   // round-to-nearest-even
  return (unsigned short)r;
}

__device__ __forceinline__ void gload_lds16(const void* g, void* l) {
  __builtin_amdgcn_global_load_lds((__attribute__((address_space(1))) void*)(void*)g,
                                   (__attribute__((address_space(3))) void*)l, 16, 0, 0);
}

__device__ __forceinline__ float mask_at(const void* mraw, int f, int idx) {
  bool m;
  if (f == 0)      m = ((const int*)mraw)[idx] != 0;
  else if (f == 1) m = ((const float*)mraw)[idx] != 0.0f;
  else             m = ((const unsigned char*)mraw)[idx] != 0;
  return m ? 1.0f : 0.0f;
}

// ---- norm (blocks 0..8191) + fused detect/zero block (block 8192) ------------
// Normalize rows -> bf16 Xn (or inv-norms only if ws too small). The extra
// block detects mask dtype (bool8 / int32 / f32 0-1) and zeroes accumulators,
// replacing a memset dispatch and a detect dispatch.
__global__ __launch_bounds__(256) void norm_kernel(const float* __restrict__ embeds,
                                                   unsigned short* __restrict__ xn,
                                                   float* __restrict__ invn,
                                                   int writeXn,
                                                   const unsigned int* __restrict__ mraw,
                                                   int* __restrict__ flag,
                                                   float* __restrict__ num,
                                                   float* __restrict__ cnt,
                                                   int* __restrict__ done) {
  __shared__ int okInt, okF32;
  if (blockIdx.x == NORM_BLOCKS) {
    // ---- detect + zero block ----
    if (threadIdx.x == 0) { okInt = 1; okF32 = 1; }
    __syncthreads();
    int badI = 0, badF = 0;
    for (int i = threadIdx.x; i < 8192; i += 256) {   // scan 32KB: safe under all layouts
      unsigned v = mraw[i];
      if (v != 0u && v != 1u) badI = 1;
      if (v != 0u && v != 0x3F800000u) badF = 1;
    }
    if (badI) atomicAnd(&okInt, 0);
    if (badF) atomicAnd(&okF32, 0);
    if (threadIdx.x < BSZ) { num[threadIdx.x] = 0.0f; cnt[threadIdx.x] = 0.0f; }
    __syncthreads();
    if (threadIdx.x == 0) { *flag = okInt ? 0 : (okF32 ? 1 : 2); *done = 0; }
    return;
  }
  int w = threadIdx.x >> 6, lane = threadIdx.x & 63;
  int row = blockIdx.x * 4 + w;                      // < 32768
  const float* src = embeds + (size_t)row * HS;
  float4 v[3];
  float ss = 0.0f;
  #pragma unroll
  for (int q = 0; q < 3; ++q) {
    v[q] = *(const float4*)(src + q * 256 + lane * 4);
    ss += v[q].x * v[q].x + v[q].y * v[q].y + v[q].z * v[q].z + v[q].w * v[q].w;
  }
  #pragma unroll
  for (int off = 32; off; off >>= 1) ss += __shfl_xor(ss, off);
  float inv = 1.0f / fmaxf(sqrtf(ss), 1e-8f);
  if (writeXn) {
    unsigned short* dst = xn + (size_t)row * HS;
    #pragma unroll
    for (int q = 0; q < 3; ++q) {
      ushort4 h;
      h.x = f2bf(v[q].x * inv); h.y = f2bf(v[q].y * inv);
      h.z = f2bf(v[q].z * inv); h.w = f2bf(v[q].w * inv);
      *(ushort4*)(dst + q * 256 + lane * 4) = h;
    }
  } else if (lane == 0) {
    invn[row] = inv;
  }
}

// ---------------- fused Gram + masked relative-loss reduction ------------------
// One WG per (batch, upper-tri 128x128 tile pair). 4 waves in 2x2, each owns a
// 64x64 sub-tile as 4x4 frags of 16x16x32 bf16 MFMA.
// R2-PROVEN inner structure (single-buffered, 2 barriers/K-step, ~19.5 KB LDS
// -> 8 blocks/CU; R3's double-buffer halved occupancy and regressed 2.2x).
// LDS tiles [128][BK] bf16, 16B-chunk XOR swizzle: chunk c of row r stored at
// pos c ^ ((r>>1)&3), applied on the pre-swizzled GLOBAL source so the
// global_load_lds dest stays linear; same XOR on the ds_read side (rule #21).
// Diagonal WGs popcount their rows into cnt[b]; the LAST WG (device-scope done
// counter) computes the final loss — no separate finish kernel.
template<int STAGE_F32>
__global__ __launch_bounds__(256) void gram_kernel(const float* __restrict__ embeds,
                                                   const unsigned short* __restrict__ xn,
                                                   const float* __restrict__ invn,
                                                   const int* __restrict__ gt,
                                                   const void* __restrict__ mraw,
                                                   const int* __restrict__ flag,
                                                   float* __restrict__ num,
                                                   float* __restrict__ cnt,
                                                   int* __restrict__ done,
                                                   float* __restrict__ out) {
  __shared__ __align__(16) unsigned short lA[BM * BK];   // 8 KB
  __shared__ __align__(16) unsigned short lB[BM * BK];   // 8 KB
  __shared__ float gtR[BM], gtC[BM], mR[BM], mC[BM], ivR[BM], ivC[BM];
  __shared__ float red[4];
  __shared__ int lastFlag;

  // XCD-aware swizzle (NWG % 8 == 0 -> bijective): contiguous tiles per XCD
  int blk = blockIdx.x;
  int swz = (blk & 7) * (NWG / 8) + (blk >> 3);
  int b = swz / TILES_PER_BATCH;
  int t = swz % TILES_PER_BATCH;
  int ti = 0;
  { int c = NTILE; while (t >= c) { t -= c; --c; ++ti; } }
  int tj = ti + t;

  const int tid = threadIdx.x;
  const int w = tid >> 6;
  const int lane = tid & 63;
  const int wr = w >> 1, wc = w & 1;
  const int Ra = ti * BM, Rb = tj * BM;

  if (tid < BM) {
    int f = *flag;
    int ia = b * NSL + Ra + tid;
    int ib = b * NSL + Rb + tid;
    gtR[tid] = (float)gt[ia]; mR[tid] = mask_at(mraw, f, ia);
    gtC[tid] = (float)gt[ib]; mC[tid] = mask_at(mraw, f, ib);
    if constexpr (STAGE_F32 != 0) { ivR[tid] = invn[ia]; ivC[tid] = invn[ib]; }
  }
  __syncthreads();   // gt/mask/ivn staged before use (ivn needed by stage)

  f32x4 acc[4][4];
  #pragma unroll
  for (int m = 0; m < 4; ++m)
    #pragma unroll
    for (int n = 0; n < 4; ++n)
      #pragma unroll
      for (int r = 0; r < 4; ++r) acc[m][n][r] = 0.0f;

  for (int ks = 0; ks < NKS; ++ks) {
    const int kbase = ks * BK;
    #pragma unroll
    for (int q = 0; q < 2; ++q) {
      int L = q * 256 + tid;            // linear 16B-chunk index 0..511
      int row = L >> 2, pos = L & 3;
      int c = pos ^ ((row >> 1) & 3);   // pre-swizzled global source
      if constexpr (STAGE_F32 == 0) {
        const unsigned short* gaA = xn + (size_t)(b * NSL + Ra + row) * HS + kbase + c * 8;
        const unsigned short* gaB = xn + (size_t)(b * NSL + Rb + row) * HS + kbase + c * 8;
        unsigned short* ldA = &lA[(q * 256 + w * 64) * 8];  // wave-uniform base
        unsigned short* ldB = &lB[(q * 256 + w * 64) * 8];
        gload_lds16(gaA, ldA);
        gload_lds16(gaB, ldB);
      } else {
        const float* gaA = embeds + (size_t)(b * NSL + Ra + row) * HS + kbase + c * 8;
        const float* gaB = embeds + (size_t)(b * NSL + Rb + row) * HS + kbase + c * 8;
        float4 a0 = *(const float4*)gaA;
        float4 a1 = *(const float4*)(gaA + 4);
        float4 b0 = *(const float4*)gaB;
        float4 b1 = *(const float4*)(gaB + 4);
        float sa = ivR[row], sb = ivC[row];
        u16x8 ha, hb;
        ha[0] = f2bf(a0.x * sa); ha[1] = f2bf(a0.y * sa);
        ha[2] = f2bf(a0.z * sa); ha[3] = f2bf(a0.w * sa);
        ha[4] = f2bf(a1.x * sa); ha[5] = f2bf(a1.y * sa);
        ha[6] = f2bf(a1.z * sa); ha[7] = f2bf(a1.w * sa);
        hb[0] = f2bf(b0.x * sb); hb[1] = f2bf(b0.y * sb);
        hb[2] = f2bf(b0.z * sb); hb[3] = f2bf(b0.w * sb);
        hb[4] = f2bf(b1.x * sb); hb[5] = f2bf(b1.y * sb);
        hb[6] = f2bf(b1.z * sb); hb[7] = f2bf(b1.w * sb);
        *(u16x8*)&lA[row * BK + pos * 8] = ha;
        *(u16x8*)&lB[row * BK + pos * 8] = hb;
      }
    }
    __syncthreads();   // staging complete (drains vmcnt/lgkmcnt before barrier)

    u16x8 af[4], bfv[4];
    const int kc = lane >> 4;
    #pragma unroll
    for (int m = 0; m < 4; ++m) {
      int row = wr * 64 + m * 16 + (lane & 15);
      af[m] = *(const u16x8*)&lA[row * BK + ((kc ^ ((row >> 1) & 3)) * 8)];
    }
    #pragma unroll
    for (int n = 0; n < 4; ++n) {
      int row = wc * 64 + n * 16 + (lane & 15);
      bfv[n] = *(const u16x8*)&lB[row * BK + ((kc ^ ((row >> 1) & 3)) * 8)];
    }
    #pragma unroll
    for (int m = 0; m < 4; ++m)
      #pragma unroll
      for (int n = 0; n < 4; ++n)
        asm volatile("v_mfma_f32_16x16x32_bf16 %0, %1, %2, %0"
                     : "+v"(acc[m][n]) : "v"(af[m]), "v"(bfv[n]));
    __syncthreads();   // compute done before next stage overwrites
  }

  asm volatile("s_nop 7\n\ts_nop 7");   // MFMA->VALU read hazard insurance

  // fused epilogue: D layout col=lane&15, row=(lane>>4)*4+reg (verified m89/m91)
  float lsum = 0.0f;
  const bool diag = (ti == tj);
  #pragma unroll
  for (int m = 0; m < 4; ++m) {
    #pragma unroll
    for (int n = 0; n < 4; ++n) {
      int ljl = wc * 64 + n * 16 + (lane & 15);
      float gj = gtC[ljl], mj = mC[ljl];
      #pragma unroll
      for (int r = 0; r < 4; ++r) {
        int lil = wr * 64 + m * 16 + (lane >> 4) * 4 + r;
        float gi = gtR[lil], mi_ = mR[lil];
        float cosd = 1.0f - acc[m][n][r];
        float vd = 2.0f * fabsf(gi - gj) / (fabsf(gi) + fabsf(gj) + 1e-18f);
        float d = cosd - vd;
        float pm = mi_ * mj;
        if (diag) pm = (lil < ljl) ? pm : 0.0f;   // strict upper triangle
        lsum += d * d * pm;
      }
    }
  }
  #pragma unroll
  for (int off = 32; off; off >>= 1) lsum += __shfl_down(lsum, off);
  if (lane == 0) red[w] = lsum;
  __syncthreads();
  if (tid == 0) atomicAdd(&num[b], red[0] + red[1] + red[2] + red[3]);

  // diagonal WGs contribute this 128-row slice's mask popcount
  if (diag) {   // WG-uniform condition -> barriers inside are legal
    __syncthreads();   // tid0's read of red[] for num must complete before reuse
    float pc = (tid < BM) ? mR[tid] : 0.0f;
    #pragma unroll
    for (int off = 32; off; off >>= 1) pc += __shfl_down(pc, off);
    if (lane == 0) red[w] = pc;
    __syncthreads();
    if (tid == 0) atomicAdd(&cnt[b], red[0] + red[1] + red[2] + red[3]);
  }

  // completion: last WG computes the loss (device-scope atomics, m20/G12)
  __threadfence();
  if (tid == 0) {
    int old = atomicAdd(done, 1);
    lastFlag = (old == NWG - 1);
  }
  __syncthreads();
  if (lastFlag && w == 0) {
    float v = 0.0f;
    if (lane < BSZ) {
      float n = atomicAdd(&num[lane], 0.0f);   // coherent read-latest
      float c = atomicAdd(&cnt[lane], 0.0f);
      float den = 0.5f * c * (c - 1.0f) + 1e-13f;   // sum(pair_mask) == C(m,2)
      v = sqrtf(n / den);
    }
    #pragma unroll
    for (int off = 32; off; off >>= 1) v += __shfl_down(v, off);
    if (lane == 0) out[0] = v * (1.0f / 32.0f);
  }
}

extern "C" void kernel_launch(void* const* d_in, const int* in_sizes, int n_in,
                              void* d_out, int out_size, void* d_ws, size_t ws_size,
                              hipStream_t stream) {
  const float* embeds = (const float*)d_in[0];
  const int* gt = (const int*)d_in[1];
  const void* mask = d_in[2];
  float* out = (float*)d_out;

  char* ws = (char*)d_ws;
  float* num   = (float*)(ws + 0);                 // 32 f32
  float* cnt   = (float*)(ws + 128);               // 32 f32
  int*   flag  = (int*)(ws + 256);
  int*   done  = (int*)(ws + 260);
  float* invn  = (float*)(ws + 512);               // 128 KB (fallback path only)
  unsigned short* xn = (unsigned short*)(ws + 512 + 131072);  // 48 MB, 16B aligned
  const size_t need_xn = 512 + 131072 + (size_t)BSZ * NSL * HS * 2;

  int useXn = (ws_size >= need_xn) ? 1 : 0;
  norm_kernel<<<NORM_BLOCKS + 1, 256, 0, stream>>>(embeds, xn, invn, useXn,
                                                   (const unsigned int*)mask,
                                                   flag, num, cnt, done);
  if (useXn)
    gram_kernel<0><<<NWG, 256, 0, stream>>>(embeds, xn, invn, gt, mask, flag, num, cnt, done, out);
  else
    gram_kernel<1><<<NWG, 256, 0, stream>>>(embeds, xn, invn, gt, mask, flag, num, cnt, done, out);
}

// Round 9
// 213.619 us; speedup vs baseline: 1.3747x; 1.3365x over previous
//
#include <hip/hip_runtime.h>
#include <math.h>

#define BSZ 32
#define NSL 1024
#define HS  768
#define BM  128
#define BK  32
#define NKS (HS / BK)            // 24
#define NTILE (NSL / BM)         // 8
#define TILES_PER_BATCH 36       // upper-tri incl diag of 8x8
#define NWG (BSZ * TILES_PER_BATCH)  // 1152
#define NORM_BLOCKS (BSZ * NSL / 4)  // 8192

typedef __attribute__((ext_vector_type(8))) unsigned short u16x8;
typedef __attribute__((ext_vector_type(4))) float f32x4;

__device__ __forceinline__ unsigned short f2bf(float x) {
  unsigned u = __float_as_uint(x);
  unsigned r = (u + 0x7FFFu + ((u >> 16) & 1u)) >> 16;   // round-to-nearest-even
  return (unsigned short)r;
}

__device__ __forceinline__ void gload_lds16(const void* g, void* l) {
  __builtin_amdgcn_global_load_lds((__attribute__((address_space(1))) void*)(void*)g,
                                   (__attribute__((address_space(3))) void*)l, 16, 0, 0);
}

__device__ __forceinline__ float mask_at(const void* mraw, int f, int idx) {
  bool m;
  if (f == 0)      m = ((const int*)mraw)[idx] != 0;
  else if (f == 1) m = ((const float*)mraw)[idx] != 0.0f;
  else             m = ((const unsigned char*)mraw)[idx] != 0;
  return m ? 1.0f : 0.0f;
}

// ---- norm (blocks 0..8191) + fused detect/zero block (block 8192) ------------
__global__ __launch_bounds__(256) void norm_kernel(const float* __restrict__ embeds,
                                                   unsigned short* __restrict__ xn,
                                                   float* __restrict__ invn,
                                                   int writeXn,
                                                   const unsigned int* __restrict__ mraw,
                                                   int* __restrict__ flag,
                                                   float* __restrict__ num,
                                                   float* __restrict__ cnt) {
  __shared__ int okInt, okF32;
  if (blockIdx.x == NORM_BLOCKS) {
    // ---- detect + zero block ----
    if (threadIdx.x == 0) { okInt = 1; okF32 = 1; }
    __syncthreads();
    int badI = 0, badF = 0;
    for (int i = threadIdx.x; i < 8192; i += 256) {   // scan 32KB: safe under all layouts
      unsigned v = mraw[i];
      if (v != 0u && v != 1u) badI = 1;
      if (v != 0u && v != 0x3F800000u) badF = 1;
    }
    if (badI) atomicAnd(&okInt, 0);
    if (badF) atomicAnd(&okF32, 0);
    if (threadIdx.x < BSZ) { num[threadIdx.x] = 0.0f; cnt[threadIdx.x] = 0.0f; }
    __syncthreads();
    if (threadIdx.x == 0) *flag = okInt ? 0 : (okF32 ? 1 : 2);
    return;
  }
  int w = threadIdx.x >> 6, lane = threadIdx.x & 63;
  int row = blockIdx.x * 4 + w;                      // < 32768
  const float* src = embeds + (size_t)row * HS;
  float4 v[3];
  float ss = 0.0f;
  #pragma unroll
  for (int q = 0; q < 3; ++q) {
    v[q] = *(const float4*)(src + q * 256 + lane * 4);
    ss += v[q].x * v[q].x + v[q].y * v[q].y + v[q].z * v[q].z + v[q].w * v[q].w;
  }
  #pragma unroll
  for (int off = 32; off; off >>= 1) ss += __shfl_xor(ss, off);
  float inv = 1.0f / fmaxf(sqrtf(ss), 1e-8f);
  if (writeXn) {
    unsigned short* dst = xn + (size_t)row * HS;
    #pragma unroll
    for (int q = 0; q < 3; ++q) {
      ushort4 h;
      h.x = f2bf(v[q].x * inv); h.y = f2bf(v[q].y * inv);
      h.z = f2bf(v[q].z * inv); h.w = f2bf(v[q].w * inv);
      *(ushort4*)(dst + q * 256 + lane * 4) = h;
    }
  } else if (lane == 0) {
    invn[row] = inv;
  }
}

// ---------------- fused Gram + masked relative-loss reduction ------------------
// One WG per (batch, upper-tri 128x128 tile pair). 4 waves in 2x2, each owns a
// 64x64 sub-tile as 4x4 frags of 16x16x32 bf16 MFMA. Single-buffered 2-barrier
// K-loop (R2-proven). LDS tiles [128][BK] bf16, 16B-chunk XOR swizzle (both-
// sides involution, rule #21). Diagonal WGs popcount rows into cnt[b].
// NO __threadfence / done-counter tail: R2-vs-R7 A/B (same K-loop, tail
// varied) showed the per-WG agent-scope fence (L2 writeback+invalidate on
// non-coherent XCD L2s) destroyed the xn panel cache for running WGs ->
// gram 2.2x slower. Separate final_kernel instead; the kernel boundary
// provides the ordering.
template<int STAGE_F32>
__global__ __launch_bounds__(256) void gram_kernel(const float* __restrict__ embeds,
                                                   const unsigned short* __restrict__ xn,
                                                   const float* __restrict__ invn,
                                                   const int* __restrict__ gt,
                                                   const void* __restrict__ mraw,
                                                   const int* __restrict__ flag,
                                                   float* __restrict__ num,
                                                   float* __restrict__ cnt) {
  __shared__ __align__(16) unsigned short lA[BM * BK];   // 8 KB
  __shared__ __align__(16) unsigned short lB[BM * BK];   // 8 KB
  __shared__ float gtR[BM], gtC[BM], mR[BM], mC[BM], ivR[BM], ivC[BM];
  __shared__ float red[4];

  // XCD-aware swizzle (NWG % 8 == 0 -> bijective): contiguous tiles per XCD
  int blk = blockIdx.x;
  int swz = (blk & 7) * (NWG / 8) + (blk >> 3);
  int b = swz / TILES_PER_BATCH;
  int t = swz % TILES_PER_BATCH;
  int ti = 0;
  { int c = NTILE; while (t >= c) { t -= c; --c; ++ti; } }
  int tj = ti + t;

  const int tid = threadIdx.x;
  const int w = tid >> 6;
  const int lane = tid & 63;
  const int wr = w >> 1, wc = w & 1;
  const int Ra = ti * BM, Rb = tj * BM;

  if (tid < BM) {
    int f = *flag;
    int ia = b * NSL + Ra + tid;
    int ib = b * NSL + Rb + tid;
    gtR[tid] = (float)gt[ia]; mR[tid] = mask_at(mraw, f, ia);
    gtC[tid] = (float)gt[ib]; mC[tid] = mask_at(mraw, f, ib);
    if constexpr (STAGE_F32 != 0) { ivR[tid] = invn[ia]; ivC[tid] = invn[ib]; }
  }
  __syncthreads();   // gt/mask/ivn staged before use (ivn needed by stage)

  f32x4 acc[4][4];
  #pragma unroll
  for (int m = 0; m < 4; ++m)
    #pragma unroll
    for (int n = 0; n < 4; ++n)
      #pragma unroll
      for (int r = 0; r < 4; ++r) acc[m][n][r] = 0.0f;

  for (int ks = 0; ks < NKS; ++ks) {
    const int kbase = ks * BK;
    #pragma unroll
    for (int q = 0; q < 2; ++q) {
      int L = q * 256 + tid;            // linear 16B-chunk index 0..511
      int row = L >> 2, pos = L & 3;
      int c = pos ^ ((row >> 1) & 3);   // pre-swizzled global source
      if constexpr (STAGE_F32 == 0) {
        const unsigned short* gaA = xn + (size_t)(b * NSL + Ra + row) * HS + kbase + c * 8;
        const unsigned short* gaB = xn + (size_t)(b * NSL + Rb + row) * HS + kbase + c * 8;
        unsigned short* ldA = &lA[(q * 256 + w * 64) * 8];  // wave-uniform base
        unsigned short* ldB = &lB[(q * 256 + w * 64) * 8];
        gload_lds16(gaA, ldA);
        gload_lds16(gaB, ldB);
      } else {
        const float* gaA = embeds + (size_t)(b * NSL + Ra + row) * HS + kbase + c * 8;
        const float* gaB = embeds + (size_t)(b * NSL + Rb + row) * HS + kbase + c * 8;
        float4 a0 = *(const float4*)gaA;
        float4 a1 = *(const float4*)(gaA + 4);
        float4 b0 = *(const float4*)gaB;
        float4 b1 = *(const float4*)(gaB + 4);
        float sa = ivR[row], sb = ivC[row];
        u16x8 ha, hb;
        ha[0] = f2bf(a0.x * sa); ha[1] = f2bf(a0.y * sa);
        ha[2] = f2bf(a0.z * sa); ha[3] = f2bf(a0.w * sa);
        ha[4] = f2bf(a1.x * sa); ha[5] = f2bf(a1.y * sa);
        ha[6] = f2bf(a1.z * sa); ha[7] = f2bf(a1.w * sa);
        hb[0] = f2bf(b0.x * sb); hb[1] = f2bf(b0.y * sb);
        hb[2] = f2bf(b0.z * sb); hb[3] = f2bf(b0.w * sb);
        hb[4] = f2bf(b1.x * sb); hb[5] = f2bf(b1.y * sb);
        hb[6] = f2bf(b1.z * sb); hb[7] = f2bf(b1.w * sb);
        *(u16x8*)&lA[row * BK + pos * 8] = ha;
        *(u16x8*)&lB[row * BK + pos * 8] = hb;
      }
    }
    __syncthreads();   // staging complete (drains vmcnt/lgkmcnt before barrier)

    u16x8 af[4], bfv[4];
    const int kc = lane >> 4;
    #pragma unroll
    for (int m = 0; m < 4; ++m) {
      int row = wr * 64 + m * 16 + (lane & 15);
      af[m] = *(const u16x8*)&lA[row * BK + ((kc ^ ((row >> 1) & 3)) * 8)];
    }
    #pragma unroll
    for (int n = 0; n < 4; ++n) {
      int row = wc * 64 + n * 16 + (lane & 15);
      bfv[n] = *(const u16x8*)&lB[row * BK + ((kc ^ ((row >> 1) & 3)) * 8)];
    }
    #pragma unroll
    for (int m = 0; m < 4; ++m)
      #pragma unroll
      for (int n = 0; n < 4; ++n)
        asm volatile("v_mfma_f32_16x16x32_bf16 %0, %1, %2, %0"
                     : "+v"(acc[m][n]) : "v"(af[m]), "v"(bfv[n]));
    __syncthreads();   // compute done before next stage overwrites
  }

  asm volatile("s_nop 7\n\ts_nop 7");   // MFMA->VALU read hazard insurance

  // fused epilogue: D layout col=lane&15, row=(lane>>4)*4+reg (verified m89/m91)
  float lsum = 0.0f;
  const bool diag = (ti == tj);
  #pragma unroll
  for (int m = 0; m < 4; ++m) {
    #pragma unroll
    for (int n = 0; n < 4; ++n) {
      int ljl = wc * 64 + n * 16 + (lane & 15);
      float gj = gtC[ljl], mj = mC[ljl];
      #pragma unroll
      for (int r = 0; r < 4; ++r) {
        int lil = wr * 64 + m * 16 + (lane >> 4) * 4 + r;
        float gi = gtR[lil], mi_ = mR[lil];
        float cosd = 1.0f - acc[m][n][r];
        float vd = 2.0f * fabsf(gi - gj) / (fabsf(gi) + fabsf(gj) + 1e-18f);
        float d = cosd - vd;
        float pm = mi_ * mj;
        if (diag) pm = (lil < ljl) ? pm : 0.0f;   // strict upper triangle
        lsum += d * d * pm;
      }
    }
  }
  #pragma unroll
  for (int off = 32; off; off >>= 1) lsum += __shfl_down(lsum, off);
  if (lane == 0) red[w] = lsum;
  __syncthreads();
  if (tid == 0) atomicAdd(&num[b], red[0] + red[1] + red[2] + red[3]);

  // diagonal WGs contribute this 128-row slice's mask popcount
  if (diag) {   // WG-uniform condition -> barriers inside are legal
    __syncthreads();   // tid0's read of red[] for num must complete before reuse
    float pc = (tid < BM) ? mR[tid] : 0.0f;
    #pragma unroll
    for (int off = 32; off; off >>= 1) pc += __shfl_down(pc, off);
    if (lane == 0) red[w] = pc;
    __syncthreads();
    if (tid == 0) atomicAdd(&cnt[b], red[0] + red[1] + red[2] + red[3]);
  }
}

// ------------------------------- finish ---------------------------------------
__global__ void final_kernel(const float* __restrict__ num, const float* __restrict__ cnt,
                             float* __restrict__ out) {
  int l = threadIdx.x;
  float v = 0.0f;
  if (l < BSZ) {
    float c = cnt[l];
    float den = 0.5f * c * (c - 1.0f) + 1e-13f;   // sum(pair_mask) == C(m,2)
    v = sqrtf(num[l] / den);
  }
  #pragma unroll
  for (int off = 32; off; off >>= 1) v += __shfl_down(v, off);
  if (l == 0) out[0] = v * (1.0f / 32.0f);
}

extern "C" void kernel_launch(void* const* d_in, const int* in_sizes, int n_in,
                              void* d_out, int out_size, void* d_ws, size_t ws_size,
                              hipStream_t stream) {
  const float* embeds = (const float*)d_in[0];
  const int* gt = (const int*)d_in[1];
  const void* mask = d_in[2];
  float* out = (float*)d_out;

  char* ws = (char*)d_ws;
  float* num   = (float*)(ws + 0);                 // 32 f32
  float* cnt   = (float*)(ws + 128);               // 32 f32
  int*   flag  = (int*)(ws + 256);
  float* invn  = (float*)(ws + 512);               // 128 KB (fallback path only)
  unsigned short* xn = (unsigned short*)(ws + 512 + 131072);  // 48 MB, 16B aligned
  const size_t need_xn = 512 + 131072 + (size_t)BSZ * NSL * HS * 2;

  int useXn = (ws_size >= need_xn) ? 1 : 0;
  norm_kernel<<<NORM_BLOCKS + 1, 256, 0, stream>>>(embeds, xn, invn, useXn,
                                                   (const unsigned int*)mask,
                                                   flag, num, cnt);
  if (useXn)
    gram_kernel<0><<<NWG, 256, 0, stream>>>(embeds, xn, invn, gt, mask, flag, num, cnt);
  else
    gram_kernel<1><<<NWG, 256, 0, stream>>>(embeds, xn, invn, gt, mask, flag, num, cnt);
  final_kernel<<<1, 64, 0, stream>>>(num, cnt, out);
}

// Round 10
// 213.404 us; speedup vs baseline: 1.3760x; 1.0010x over previous
//
#include <hip/hip_runtime.h>
#include <math.h>

#define BSZ 32
#define NSL 1024
#define HS  768
#define BM  128
#define BK  32
#define NKS (HS / BK)            // 24
#define NTILE (NSL / BM)         // 8
#define TILES_PER_BATCH 36       // upper-tri incl diag of 8x8
#define NWG (BSZ * TILES_PER_BATCH)  // 1152
#define NORM_BLOCKS (BSZ * NSL / 4)  // 8192

typedef __attribute__((ext_vector_type(8))) unsigned short u16x8;
typedef __attribute__((ext_vector_type(4))) float f32x4;

__device__ __forceinline__ unsigned short f2bf(float x) {
  unsigned u = __float_as_uint(x);
  unsigned r = (u + 0x7FFFu + ((u >> 16) & 1u)) >> 16;   // round-to-nearest-even
  return (unsigned short)r;
}

__device__ __forceinline__ void gload_lds16(const void* g, void* l) {
  __builtin_amdgcn_global_load_lds((__attribute__((address_space(1))) void*)(void*)g,
                                   (__attribute__((address_space(3))) void*)l, 16, 0, 0);
}

__device__ __forceinline__ float mask_at(const void* mraw, int f, int idx) {
  bool m;
  if (f == 0)      m = ((const int*)mraw)[idx] != 0;
  else if (f == 1) m = ((const float*)mraw)[idx] != 0.0f;
  else             m = ((const unsigned char*)mraw)[idx] != 0;
  return m ? 1.0f : 0.0f;
}

// ---- norm (blocks 0..8191) + fused detect/zero block (block 8192) ------------
__global__ __launch_bounds__(256) void norm_kernel(const float* __restrict__ embeds,
                                                   unsigned short* __restrict__ xn,
                                                   float* __restrict__ invn,
                                                   int writeXn,
                                                   const unsigned int* __restrict__ mraw,
                                                   int* __restrict__ flag,
                                                   float* __restrict__ num,
                                                   float* __restrict__ cnt) {
  __shared__ int okInt, okF32;
  if (blockIdx.x == NORM_BLOCKS) {
    // ---- detect + zero block ----
    if (threadIdx.x == 0) { okInt = 1; okF32 = 1; }
    __syncthreads();
    int badI = 0, badF = 0;
    for (int i = threadIdx.x; i < 8192; i += 256) {   // scan 32KB: safe under all layouts
      unsigned v = mraw[i];
      if (v != 0u && v != 1u) badI = 1;
      if (v != 0u && v != 0x3F800000u) badF = 1;
    }
    if (badI) atomicAnd(&okInt, 0);
    if (badF) atomicAnd(&okF32, 0);
    if (threadIdx.x < BSZ) { num[threadIdx.x] = 0.0f; cnt[threadIdx.x] = 0.0f; }
    __syncthreads();
    if (threadIdx.x == 0) *flag = okInt ? 0 : (okF32 ? 1 : 2);
    return;
  }
  int w = threadIdx.x >> 6, lane = threadIdx.x & 63;
  int row = blockIdx.x * 4 + w;                      // < 32768
  const float* src = embeds + (size_t)row * HS;
  float4 v[3];
  float ss = 0.0f;
  #pragma unroll
  for (int q = 0; q < 3; ++q) {
    v[q] = *(const float4*)(src + q * 256 + lane * 4);
    ss += v[q].x * v[q].x + v[q].y * v[q].y + v[q].z * v[q].z + v[q].w * v[q].w;
  }
  #pragma unroll
  for (int off = 32; off; off >>= 1) ss += __shfl_xor(ss, off);
  float inv = 1.0f / fmaxf(sqrtf(ss), 1e-8f);
  if (writeXn) {
    unsigned short* dst = xn + (size_t)row * HS;
    #pragma unroll
    for (int q = 0; q < 3; ++q) {
      ushort4 h;
      h.x = f2bf(v[q].x * inv); h.y = f2bf(v[q].y * inv);
      h.z = f2bf(v[q].z * inv); h.w = f2bf(v[q].w * inv);
      *(ushort4*)(dst + q * 256 + lane * 4) = h;
    }
  } else if (lane == 0) {
    invn[row] = inv;
  }
}

// ---------------- fused Gram + masked relative-loss reduction ------------------
// One WG per (batch, upper-tri 128x128 tile pair). 4 waves in 2x2, each owns a
// 64x64 sub-tile as 4x4 frags of 16x16x32 bf16 MFMA.
// T3-minimum 2-phase K-loop (fence-free retest): issue next tile's
// global_load_lds BEFORE current tile's ds_read+MFMA; ONE barrier per K-step
// (vs 2 in R9's sbuf loop). R4-vs-R7 showed dbuf was neutral under the fence;
// the fence was the 2.2x regression (removed in R9, confirmed). LDS ~36 KB ->
// 4 WG/CU (work = 4.5 WG/CU). 16B-chunk XOR swizzle both-sides (rule #21).
// NO __threadfence / done-counter tail (R7 lesson). Separate final_kernel.
template<int STAGE_F32>
__global__ __launch_bounds__(256) void gram_kernel(const float* __restrict__ embeds,
                                                   const unsigned short* __restrict__ xn,
                                                   const float* __restrict__ invn,
                                                   const int* __restrict__ gt,
                                                   const void* __restrict__ mraw,
                                                   const int* __restrict__ flag,
                                                   float* __restrict__ num,
                                                   float* __restrict__ cnt) {
  __shared__ __align__(16) unsigned short lA[2][BM * BK];   // 2 x 8 KB
  __shared__ __align__(16) unsigned short lB[2][BM * BK];   // 2 x 8 KB
  __shared__ float gtR[BM], gtC[BM], mR[BM], mC[BM], ivR[BM], ivC[BM];
  __shared__ float red[4];

  // XCD-aware swizzle (NWG % 8 == 0 -> bijective): contiguous tiles per XCD
  int blk = blockIdx.x;
  int swz = (blk & 7) * (NWG / 8) + (blk >> 3);
  int b = swz / TILES_PER_BATCH;
  int t = swz % TILES_PER_BATCH;
  int ti = 0;
  { int c = NTILE; while (t >= c) { t -= c; --c; ++ti; } }
  int tj = ti + t;

  const int tid = threadIdx.x;
  const int w = tid >> 6;
  const int lane = tid & 63;
  const int wr = w >> 1, wc = w & 1;
  const int Ra = ti * BM, Rb = tj * BM;

  if (tid < BM) {
    int f = *flag;
    int ia = b * NSL + Ra + tid;
    int ib = b * NSL + Rb + tid;
    gtR[tid] = (float)gt[ia]; mR[tid] = mask_at(mraw, f, ia);
    gtC[tid] = (float)gt[ib]; mC[tid] = mask_at(mraw, f, ib);
    if constexpr (STAGE_F32 != 0) { ivR[tid] = invn[ia]; ivC[tid] = invn[ib]; }
  }

  f32x4 acc[4][4];
  #pragma unroll
  for (int m = 0; m < 4; ++m)
    #pragma unroll
    for (int n = 0; n < 4; ++n)
      #pragma unroll
      for (int r = 0; r < 4; ++r) acc[m][n][r] = 0.0f;

  auto stage = [&](int buf, int ks) {
    const int kbase = ks * BK;
    #pragma unroll
    for (int q = 0; q < 2; ++q) {
      int L = q * 256 + tid;            // linear 16B-chunk index 0..511
      int row = L >> 2, pos = L & 3;
      int c = pos ^ ((row >> 1) & 3);   // pre-swizzled global source
      if constexpr (STAGE_F32 == 0) {
        const unsigned short* gaA = xn + (size_t)(b * NSL + Ra + row) * HS + kbase + c * 8;
        const unsigned short* gaB = xn + (size_t)(b * NSL + Rb + row) * HS + kbase + c * 8;
        unsigned short* ldA = &lA[buf][(q * 256 + w * 64) * 8];  // wave-uniform base
        unsigned short* ldB = &lB[buf][(q * 256 + w * 64) * 8];
        gload_lds16(gaA, ldA);
        gload_lds16(gaB, ldB);
      } else {
        const float* gaA = embeds + (size_t)(b * NSL + Ra + row) * HS + kbase + c * 8;
        const float* gaB = embeds + (size_t)(b * NSL + Rb + row) * HS + kbase + c * 8;
        float4 a0 = *(const float4*)gaA;
        float4 a1 = *(const float4*)(gaA + 4);
        float4 b0 = *(const float4*)gaB;
        float4 b1 = *(const float4*)(gaB + 4);
        float sa = ivR[row], sb = ivC[row];
        u16x8 ha, hb;
        ha[0] = f2bf(a0.x * sa); ha[1] = f2bf(a0.y * sa);
        ha[2] = f2bf(a0.z * sa); ha[3] = f2bf(a0.w * sa);
        ha[4] = f2bf(a1.x * sa); ha[5] = f2bf(a1.y * sa);
        ha[6] = f2bf(a1.z * sa); ha[7] = f2bf(a1.w * sa);
        hb[0] = f2bf(b0.x * sb); hb[1] = f2bf(b0.y * sb);
        hb[2] = f2bf(b0.z * sb); hb[3] = f2bf(b0.w * sb);
        hb[4] = f2bf(b1.x * sb); hb[5] = f2bf(b1.y * sb);
        hb[6] = f2bf(b1.z * sb); hb[7] = f2bf(b1.w * sb);
        *(u16x8*)&lA[buf][row * BK + pos * 8] = ha;
        *(u16x8*)&lB[buf][row * BK + pos * 8] = hb;
      }
    }
  };

  if constexpr (STAGE_F32 != 0) __syncthreads();   // ivR/ivC ready before stage
  stage(0, 0);
  __syncthreads();   // prologue drain (also covers gtR/mR stores)

  int cur = 0;
  for (int ks = 0; ks < NKS; ++ks) {
    if (ks + 1 < NKS) stage(cur ^ 1, ks + 1);   // issue-early: in flight across compute

    u16x8 af[4], bfv[4];
    const int kc = lane >> 4;
    #pragma unroll
    for (int m = 0; m < 4; ++m) {
      int row = wr * 64 + m * 16 + (lane & 15);
      af[m] = *(const u16x8*)&lA[cur][row * BK + ((kc ^ ((row >> 1) & 3)) * 8)];
    }
    #pragma unroll
    for (int n = 0; n < 4; ++n) {
      int row = wc * 64 + n * 16 + (lane & 15);
      bfv[n] = *(const u16x8*)&lB[cur][row * BK + ((kc ^ ((row >> 1) & 3)) * 8)];
    }
    #pragma unroll
    for (int m = 0; m < 4; ++m)
      #pragma unroll
      for (int n = 0; n < 4; ++n)
        asm volatile("v_mfma_f32_16x16x32_bf16 %0, %1, %2, %0"
                     : "+v"(acc[m][n]) : "v"(af[m]), "v"(bfv[n]));
    __syncthreads();   // next buffer staged + this buffer's reads complete
    cur ^= 1;
  }

  asm volatile("s_nop 7\n\ts_nop 7");   // MFMA->VALU read hazard insurance

  // fused epilogue: D layout col=lane&15, row=(lane>>4)*4+reg (verified m89/m91)
  float lsum = 0.0f;
  const bool diag = (ti == tj);
  #pragma unroll
  for (int m = 0; m < 4; ++m) {
    #pragma unroll
    for (int n = 0; n < 4; ++n) {
      int ljl = wc * 64 + n * 16 + (lane & 15);
      float gj = gtC[ljl], mj = mC[ljl];
      #pragma unroll
      for (int r = 0; r < 4; ++r) {
        int lil = wr * 64 + m * 16 + (lane >> 4) * 4 + r;
        float gi = gtR[lil], mi_ = mR[lil];
        float cosd = 1.0f - acc[m][n][r];
        float vd = 2.0f * fabsf(gi - gj) / (fabsf(gi) + fabsf(gj) + 1e-18f);
        float d = cosd - vd;
        float pm = mi_ * mj;
        if (diag) pm = (lil < ljl) ? pm : 0.0f;   // strict upper triangle
        lsum += d * d * pm;
      }
    }
  }
  #pragma unroll
  for (int off = 32; off; off >>= 1) lsum += __shfl_down(lsum, off);
  if (lane == 0) red[w] = lsum;
  __syncthreads();
  if (tid == 0) atomicAdd(&num[b], red[0] + red[1] + red[2] + red[3]);

  // diagonal WGs contribute this 128-row slice's mask popcount
  if (diag) {   // WG-uniform condition -> barriers inside are legal
    __syncthreads();   // tid0's read of red[] for num must complete before reuse
    float pc = (tid < BM) ? mR[tid] : 0.0f;
    #pragma unroll
    for (int off = 32; off; off >>= 1) pc += __shfl_down(pc, off);
    if (lane == 0) red[w] = pc;
    __syncthreads();
    if (tid == 0) atomicAdd(&cnt[b], red[0] + red[1] + red[2] + red[3]);
  }
}

// ------------------------------- finish ---------------------------------------
__global__ void final_kernel(const float* __restrict__ num, const float* __restrict__ cnt,
                             float* __restrict__ out) {
  int l = threadIdx.x;
  float v = 0.0f;
  if (l < BSZ) {
    float c = cnt[l];
    float den = 0.5f * c * (c - 1.0f) + 1e-13f;   // sum(pair_mask) == C(m,2)
    v = sqrtf(num[l] / den);
  }
  #pragma unroll
  for (int off = 32; off; off >>= 1) v += __shfl_down(v, off);
  if (l == 0) out[0] = v * (1.0f / 32.0f);
}

extern "C" void kernel_launch(void* const* d_in, const int* in_sizes, int n_in,
                              void* d_out, int out_size, void* d_ws, size_t ws_size,
                              hipStream_t stream) {
  const float* embeds = (const float*)d_in[0];
  const int* gt = (const int*)d_in[1];
  const void* mask = d_in[2];
  float* out = (float*)d_out;

  char* ws = (char*)d_ws;
  float* num   = (float*)(ws + 0);                 // 32 f32
  float* cnt   = (float*)(ws + 128);               // 32 f32
  int*   flag  = (int*)(ws + 256);
  float* invn  = (float*)(ws + 512);               // 128 KB (fallback path only)
  unsigned short* xn = (unsigned short*)(ws + 512 + 131072);  // 48 MB, 16B aligned
  const size_t need_xn = 512 + 131072 + (size_t)BSZ * NSL * HS * 2;

  int useXn = (ws_size >= need_xn) ? 1 : 0;
  norm_kernel<<<NORM_BLOCKS + 1, 256, 0, stream>>>(embeds, xn, invn, useXn,
                                                   (const unsigned int*)mask,
                                                   flag, num, cnt);
  if (useXn)
    gram_kernel<0><<<NWG, 256, 0, stream>>>(embeds, xn, invn, gt, mask, flag, num, cnt);
  else
    gram_kernel<1><<<NWG, 256, 0, stream>>>(embeds, xn, invn, gt, mask, flag, num, cnt);
  final_kernel<<<1, 64, 0, stream>>>(num, cnt, out);
}